// Round 15
// baseline (123.463 us; speedup 1.0000x reference)
//
#include <hip/hip_runtime.h>
#include <hip/hip_bf16.h>
#include <stdint.h>

typedef short vbf16x8 __attribute__((ext_vector_type(8)));
typedef float vf32x4 __attribute__((ext_vector_type(4)));
typedef unsigned short u16;

__device__ __forceinline__ float bf2f(u16 u) {
  union { unsigned int i; float f; } v; v.i = ((unsigned int)u) << 16; return v.f;
}
__device__ __forceinline__ u16 f2bf(float f) {
  union { float f; unsigned int i; } v; v.f = f;
  return (u16)((v.i + 0x7fffu + ((v.i >> 16) & 1u)) >> 16);
}
__device__ __forceinline__ void gld16(const void* g, void* l) {
  __builtin_amdgcn_global_load_lds((const __attribute__((address_space(1))) void*)g,
                                   (__attribute__((address_space(3))) void*)l, 16, 0, 0);
}
template<int N> __device__ __forceinline__ void wait_vmcnt() {
  asm volatile("s_waitcnt vmcnt(%0)" :: "n"(N) : "memory");
}
__device__ __forceinline__ vbf16x8 ldsv(const u16* p) { return *(const vbf16x8*)p; }

// ---- W fp32 [512][512] -> bf16
__global__ __launch_bounds__(256) void k_convw(const float* __restrict__ W, u16* __restrict__ Wb) {
  int i = blockIdx.x * 256 + threadIdx.x;
  float4 x = ((const float4*)W)[i];
  ushort4 h;
  h.x = f2bf(x.x); h.y = f2bf(x.y); h.z = f2bf(x.z); h.w = f2bf(x.w);
  ((ushort4*)Wb)[i] = h;
}

// ---- input fp32 [8][2048][512] -> Abf bf16 (same layout) + Vt bf16 [8][512][2048]
__global__ __launch_bounds__(256) void k_prep(const float* __restrict__ in,
                                              u16* __restrict__ Abf, u16* __restrict__ Vt) {
  __shared__ u16 Ts[64][72];
  const int tid = threadIdx.x;
  const int n0 = blockIdx.x * 64, d0 = blockIdx.y * 64, b = blockIdx.z;
  const float* src = in + ((long long)b * 2048 + n0) * 512 + d0;
#pragma unroll
  for (int j = 0; j < 4; ++j) {
    int chunk = tid + 256 * j;
    int r = chunk >> 4, c = (chunk & 15) * 4;
    float4 x = *(const float4*)(src + (long long)r * 512 + c);
    ushort4 h;
    h.x = f2bf(x.x); h.y = f2bf(x.y); h.z = f2bf(x.z); h.w = f2bf(x.w);
    *(ushort4*)(Abf + ((long long)b * 2048 + n0 + r) * 512 + d0 + c) = h;
    Ts[c + 0][r] = h.x; Ts[c + 1][r] = h.y; Ts[c + 2][r] = h.z; Ts[c + 3][r] = h.w;
  }
  __syncthreads();
#pragma unroll
  for (int j = 0; j < 2; ++j) {
    int chunk = tid + 256 * j;
    int dr = chunk >> 3, c8 = (chunk & 7) * 8;
    vbf16x8 w = *(const vbf16x8*)&Ts[dr][c8];
    *(vbf16x8*)(Vt + ((long long)b * 512 + d0 + dr) * 2048 + n0 + c8) = w;
  }
}

// ---- row norms of X: D[row] = ||x_row||^2 ; one wave per row (16384 rows)
__global__ __launch_bounds__(256) void k_rownorm(const u16* __restrict__ X,
                                                 float* __restrict__ D) {
  const int row = blockIdx.x * 4 + (threadIdx.x >> 6);
  const int lane = threadIdx.x & 63;
  vbf16x8 v = *(const vbf16x8*)(X + (long long)row * 512 + lane * 8);
  float s = 0.0f;
#pragma unroll
  for (int j = 0; j < 8; ++j) { float x = bf2f((u16)v[j]); s = fmaf(x, x, s); }
  for (int o = 1; o < 64; o <<= 1) s += __shfl_xor(s, o);
  if (lane == 0) D[row] = s;
}

// ---- row sums of P (fallback path): L[row] = sum_col P[row][col]
__global__ __launch_bounds__(256) void k_sumP(const u16* __restrict__ P,
                                              float* __restrict__ L) {
  const int row = blockIdx.x * 4 + (threadIdx.x >> 6);
  const int lane = threadIdx.x & 63;
  const u16* p = P + (long long)row * 2048;
  float s = 0.0f;
#pragma unroll
  for (int o = 0; o < 4; ++o) {
    vbf16x8 v = *(const vbf16x8*)(p + o * 512 + lane * 8);
#pragma unroll
    for (int j = 0; j < 8; ++j) s += bf2f((u16)v[j]);
  }
  for (int o = 1; o < 64; o <<= 1) s += __shfl_xor(s, o);
  if (lane == 0) L[row] = s;
}

// ---- reduce L32 partials: L[row] = sum of 32 per-slice partials (fused path)
__global__ __launch_bounds__(256) void k_sumL(const float* __restrict__ L32,
                                              float* __restrict__ L) {
  const int row = blockIdx.x * 256 + threadIdx.x;     // 64 blocks x 256 = 16384
  const float4* p = (const float4*)(L32 + (long long)row * 32);
  float s = 0.0f;
#pragma unroll
  for (int i = 0; i < 8; ++i) {
    float4 v = p[i];
    s += (v.x + v.y) + (v.z + v.w);
  }
  L[row] = s;
}

// ========== 256x128 GEMM (C = A @ Bt^T), BK=64, depth-2 tile prefetch ==========
// NORM=true (PV): divides output rows by L[z*2048+row].
__device__ __forceinline__ void sround(const u16* g, int K, int k0, u16* ldsbuf,
                                       int r, int srow, int scol, int wv) {
  gld16(g + (long long)(r * 64 + srow) * K + k0 + scol, ldsbuf + r * 4096 + wv * 512);
}

template<bool OUTBF, bool BIAS, int MAP, bool NORM>
__global__ __launch_bounds__(512, 2) void k_gemm(const u16* __restrict__ A,
                                                 const u16* __restrict__ Bt,
                                                 const float* __restrict__ bias,
                                                 const float* __restrict__ L,
                                                 void* __restrict__ Cout,
                                                 int M, int N, int K,
                                                 long long sA, long long sB, long long sC) {
  __shared__ __align__(16) u16 As[3 * 16384];   // 3 x 256x64
  __shared__ __align__(16) u16 Bs[3 * 8192];    // 3 x 128x64

  const int tid = threadIdx.x, lane = tid & 63, wv = tid >> 6;
  const int wr = wv >> 2, wc = wv & 3;

  const int lin = blockIdx.x;
  const int xcd = lin & 7, idx = lin >> 3;
  int zb, browi, bcoli;
  if constexpr (MAP == 1) { zb = 0; browi = xcd * 8 + (idx >> 2); bcoli = idx & 3; }  // GEMM1: 256 wg
  else { zb = xcd; browi = idx >> 2; bcoli = idx & 3; }                               // PV: 256 wg
  const int brow = browi * 256, bcol = bcoli * 128;
  const long long z = zb;

  const u16* gA = A + z * sA + (long long)brow * K;
  const u16* gB = Bt + z * sB + (long long)bcol * K;
  const int NT = K >> 6;

  const int srow = wv * 8 + (lane >> 3);
  const int scol = (((lane & 7) ^ ((lane >> 3) & 7)) << 3);
  const int rd0 = (lane & 15) * 64 + ((((lane >> 4)) ^ (lane & 7)) << 3);
  const int wrb = wr * 8192;
  const int wcb = wc * 2048;

  vf32x4 acc[8][2] = {};
  vbf16x8 afr[4], bfr[2];

  u16 *A0 = As, *A1 = As + 16384, *A2 = As + 32768;
  u16 *B0 = Bs, *B1 = Bs + 8192, *B2 = Bs + 16384;

  sround(gA, K, 0, A0, 0, srow, scol, wv);
  sround(gA, K, 0, A0, 1, srow, scol, wv);
  sround(gA, K, 0, A0, 2, srow, scol, wv);
  sround(gA, K, 0, A0, 3, srow, scol, wv);
  sround(gB, K, 0, B0, 0, srow, scol, wv);
  sround(gB, K, 0, B0, 1, srow, scol, wv);
  sround(gA, K, 64, A1, 0, srow, scol, wv);
  sround(gA, K, 64, A1, 1, srow, scol, wv);
  sround(gA, K, 64, A1, 2, srow, scol, wv);
  sround(gA, K, 64, A1, 3, srow, scol, wv);
  sround(gB, K, 64, B1, 0, srow, scol, wv);
  sround(gB, K, 64, B1, 1, srow, scol, wv);

  for (int t = 0; t < NT; ++t) {
    const int k2 = (t + 2) * 64;
    const bool st = (t + 2 < NT);

    if (t < NT - 1) wait_vmcnt<6>(); else wait_vmcnt<0>();
    __builtin_amdgcn_sched_barrier(0);
    __builtin_amdgcn_s_barrier();
    __builtin_amdgcn_sched_barrier(0);

    // ---- phase 0: kh0, m0-3
#pragma unroll
    for (int n = 0; n < 2; ++n) bfr[n] = ldsv(B0 + wcb + n * 1024 + rd0);
#pragma unroll
    for (int i = 0; i < 4; ++i) afr[i] = ldsv(A0 + wrb + i * 1024 + rd0);
    if (st) { sround(gA, K, k2, A2, 0, srow, scol, wv); sround(gA, K, k2, A2, 1, srow, scol, wv); }
    __builtin_amdgcn_s_setprio(1);
#pragma unroll
    for (int i = 0; i < 4; ++i)
#pragma unroll
      for (int n = 0; n < 2; ++n)
        acc[i][n] = __builtin_amdgcn_mfma_f32_16x16x32_bf16(afr[i], bfr[n], acc[i][n], 0, 0, 0);
    __builtin_amdgcn_s_setprio(0);

    // ---- phase 1: kh0, m4-7
#pragma unroll
    for (int i = 0; i < 4; ++i) afr[i] = ldsv(A0 + wrb + (4 + i) * 1024 + rd0);
    if (st) sround(gA, K, k2, A2, 2, srow, scol, wv);
    __builtin_amdgcn_s_setprio(1);
#pragma unroll
    for (int i = 0; i < 4; ++i)
#pragma unroll
      for (int n = 0; n < 2; ++n)
        acc[4 + i][n] = __builtin_amdgcn_mfma_f32_16x16x32_bf16(afr[i], bfr[n], acc[4 + i][n], 0, 0, 0);
    __builtin_amdgcn_s_setprio(0);

    // ---- phase 2: kh1, m0-3
#pragma unroll
    for (int n = 0; n < 2; ++n) bfr[n] = ldsv(B0 + wcb + n * 1024 + (rd0 ^ 32));
#pragma unroll
    for (int i = 0; i < 4; ++i) afr[i] = ldsv(A0 + wrb + i * 1024 + (rd0 ^ 32));
    if (st) { sround(gA, K, k2, A2, 3, srow, scol, wv); sround(gB, K, k2, B2, 0, srow, scol, wv); }
    __builtin_amdgcn_s_setprio(1);
#pragma unroll
    for (int i = 0; i < 4; ++i)
#pragma unroll
      for (int n = 0; n < 2; ++n)
        acc[i][n] = __builtin_amdgcn_mfma_f32_16x16x32_bf16(afr[i], bfr[n], acc[i][n], 0, 0, 0);
    __builtin_amdgcn_s_setprio(0);

    // ---- phase 3: kh1, m4-7
#pragma unroll
    for (int i = 0; i < 4; ++i) afr[i] = ldsv(A0 + wrb + (4 + i) * 1024 + (rd0 ^ 32));
    if (st) sround(gB, K, k2, B2, 1, srow, scol, wv);
    __builtin_amdgcn_s_setprio(1);
#pragma unroll
    for (int i = 0; i < 4; ++i)
#pragma unroll
      for (int n = 0; n < 2; ++n)
        acc[4 + i][n] = __builtin_amdgcn_mfma_f32_16x16x32_bf16(afr[i], bfr[n], acc[4 + i][n], 0, 0, 0);
    __builtin_amdgcn_s_setprio(0);

    u16* ta = A0; A0 = A1; A1 = A2; A2 = ta;
    u16* tb = B0; B0 = B1; B1 = B2; B2 = tb;
  }

  // ---- epilogue: C/D layout col=lane&15, row=(lane>>4)*4+r; NORM: /L[row]
  const long long zc = z * sC;
#pragma unroll
  for (int m = 0; m < 8; ++m) {
    const int row0 = brow + wr * 128 + m * 16 + (lane >> 4) * 4;
#pragma unroll
    for (int n = 0; n < 2; ++n) {
      const int col = bcol + wc * 32 + n * 16 + (lane & 15);
      const float bv = BIAS ? bias[col] : 0.0f;
#pragma unroll
      for (int r = 0; r < 4; ++r) {
        float v = acc[m][n][r] + bv;
        if constexpr (NORM) v = v / L[z * 2048 + row0 + r];
        const long long off = zc + (long long)(row0 + r) * N + col;
        if (OUTBF) ((u16*)Cout)[off] = f2bf(v);
        else       ((float*)Cout)[off] = v;
      }
    }
  }
}

// ===== 256x256 S-GEMM -> P = exp(S - d), BK=32, depth-2, swizzled ============
// Main loop identical to R10 (0 conflicts). Epilogue: exp (R13-proven) and,
// when FUSEL, per-row 64-col partial sums of the bf16-rounded p values ->
// L32[z][row][bcoli*4+wc]  (in-register data; avoids k_sumP's 64 MiB re-read).
__device__ __forceinline__ void sr32(const u16* g, int K, int k0, u16* ldsbuf,
                                     int r, int srow, int scol, int wv) {
  gld16(g + (long long)(r * 128 + srow) * K + k0 + scol, ldsbuf + r * 4096 + wv * 512);
}

template<bool FUSEL>
__global__ __launch_bounds__(512, 2) void k_gemmS(const u16* __restrict__ X,
                                                  const float* __restrict__ D,
                                                  u16* __restrict__ P,
                                                  float* __restrict__ L32) {
  constexpr int K = 512, N = 2048;
  __shared__ __align__(16) u16 As[3 * 8192];    // 3 x 256x32
  __shared__ __align__(16) u16 Bs[3 * 8192];    // 3 x 256x32

  const int tid = threadIdx.x, lane = tid & 63, wv = tid >> 6;
  const int wr = wv >> 2, wc = wv & 3;

  const int lin = blockIdx.x;
  const int xcd = lin & 7, idx = lin >> 3;
  const int brow = (idx >> 3) * 256, bcol = (idx & 7) * 256;
  const long long z = xcd;

  const u16* gA = X + z * (2048LL * 512) + (long long)brow * K;
  const u16* gB = X + z * (2048LL * 512) + (long long)bcol * K;
  const int NT = K >> 5;                // 16 tiles

  const int srow = wv * 16 + (lane >> 2);
  const int scol = (((lane & 3) ^ ((lane >> 3) & 3)) << 3);
  const int rd = (lane & 15) * 32 + ((((lane >> 4)) ^ (((lane & 15) >> 1) & 3)) << 3);
  const int wrb = wr * 4096;
  const int wcb = wc * 2048;

  vf32x4 acc[8][4] = {};
  vbf16x8 afr[4], bfr[4];

  u16 *A0 = As, *A1 = As + 8192, *A2 = As + 16384;
  u16 *B0 = Bs, *B1 = Bs + 8192, *B2 = Bs + 16384;

  sr32(gA, K, 0, A0, 0, srow, scol, wv);
  sr32(gA, K, 0, A0, 1, srow, scol, wv);
  sr32(gB, K, 0, B0, 0, srow, scol, wv);
  sr32(gB, K, 0, B0, 1, srow, scol, wv);
  sr32(gA, K, 32, A1, 0, srow, scol, wv);
  sr32(gA, K, 32, A1, 1, srow, scol, wv);
  sr32(gB, K, 32, B1, 0, srow, scol, wv);
  sr32(gB, K, 32, B1, 1, srow, scol, wv);

  for (int t = 0; t < NT; ++t) {
    const int k2 = (t + 2) * 32;
    const bool st = (t + 2 < NT);

    if (t < NT - 1) wait_vmcnt<4>(); else wait_vmcnt<0>();
    __builtin_amdgcn_sched_barrier(0);
    __builtin_amdgcn_s_barrier();
    __builtin_amdgcn_sched_barrier(0);

    // ---- phase 0: read B n0-3 + A m0-3; stage A(t+2); MFMA m0-3 x n0-3
#pragma unroll
    for (int n = 0; n < 4; ++n) bfr[n] = ldsv(B0 + wcb + n * 512 + rd);
#pragma unroll
    for (int i = 0; i < 4; ++i) afr[i] = ldsv(A0 + wrb + i * 512 + rd);
    if (st) { sr32(gA, K, k2, A2, 0, srow, scol, wv); sr32(gA, K, k2, A2, 1, srow, scol, wv); }
    __builtin_amdgcn_s_setprio(1);
#pragma unroll
    for (int i = 0; i < 4; ++i)
#pragma unroll
      for (int n = 0; n < 4; ++n)
        acc[i][n] = __builtin_amdgcn_mfma_f32_16x16x32_bf16(afr[i], bfr[n], acc[i][n], 0, 0, 0);
    __builtin_amdgcn_s_setprio(0);

    // ---- phase 1: read A m4-7; stage B(t+2); MFMA m4-7 x n0-3
#pragma unroll
    for (int i = 0; i < 4; ++i) afr[i] = ldsv(A0 + wrb + (4 + i) * 512 + rd);
    if (st) { sr32(gB, K, k2, B2, 0, srow, scol, wv); sr32(gB, K, k2, B2, 1, srow, scol, wv); }
    __builtin_amdgcn_s_setprio(1);
#pragma unroll
    for (int i = 0; i < 4; ++i)
#pragma unroll
      for (int n = 0; n < 4; ++n)
        acc[4 + i][n] = __builtin_amdgcn_mfma_f32_16x16x32_bf16(afr[i], bfr[n], acc[4 + i][n], 0, 0, 0);
    __builtin_amdgcn_s_setprio(0);

    u16* ta = A0; A0 = A1; A1 = A2; A2 = ta;
    u16* tb = B0; B0 = B1; B1 = B2; B2 = tb;
  }

  // ---- epilogue: P = exp(s - d) (+ per-row partial sums when FUSEL)
  const float* Dz = D + z * 2048;
  const long long zc = z * (2048LL * 2048);
  float* L32z = FUSEL ? (L32 + z * (2048LL * 32)) : nullptr;
#pragma unroll
  for (int m = 0; m < 8; ++m) {
    const int row0 = brow + wr * 128 + m * 16 + (lane >> 4) * 4;
#pragma unroll
    for (int r = 0; r < 4; ++r) {
      const float dv = Dz[row0 + r];
      float rs = 0.0f;
#pragma unroll
      for (int n = 0; n < 4; ++n) {
        const int col = bcol + wc * 64 + n * 16 + (lane & 15);
        const float p = __expf(acc[m][n][r] - dv);
        const u16 h = f2bf(p);
        P[zc + (long long)(row0 + r) * N + col] = h;
        if constexpr (FUSEL) rs += bf2f(h);      // sum the SAME rounded values PV consumes
      }
      if constexpr (FUSEL) {
        rs += __shfl_xor(rs, 1);
        rs += __shfl_xor(rs, 2);
        rs += __shfl_xor(rs, 4);
        rs += __shfl_xor(rs, 8);
        if ((lane & 15) == 0)
          L32z[(long long)(row0 + r) * 32 + (idx & 7) * 4 + wc] = rs;
      }
    }
  }
}

extern "C" void kernel_launch(void* const* d_in, const int* in_sizes, int n_in,
                              void* d_out, int out_size, void* d_ws, size_t ws_size,
                              hipStream_t stream) {
  const float* input = (const float*)d_in[0];   // [8][2048][512] f32
  const float* W     = (const float*)d_in[1];   // [512][512] f32
  const float* bias  = (const float*)d_in[2];   // [512] f32
  float* out = (float*)d_out;                   // [8][2048][512] f32

  char* ws = (char*)d_ws;
  u16* Xbf = (u16*)(ws);                        // 16 MiB
  u16* Vt  = (u16*)(ws + 16777216);             // 16 MiB
  u16* P   = (u16*)(ws + 2LL * 16777216);       // 64 MiB
  u16* Abf = (u16*)(ws + 2LL * 16777216);       // alias (first 16 MiB of P)
  u16* Wb  = (u16*)(ws + 3LL * 16777216);       // alias (0.5 MiB inside P)
  float* D = out;                               // 64 KB in out head (dead before PV)
  float* L = (float*)ws;                        // 64 KB in Xbf head (Xbf dead after S)
  float* L32 = (float*)(ws + 6LL * 16777216);   // 2 MiB at ws+96MiB (fused path only)
  const bool fused = ws_size >= (99ull << 20);  // need 96 MiB + 2 MiB

  // 1) W -> bf16
  k_convw<<<256, 256, 0, stream>>>(W, Wb);
  // 2) input -> bf16 + transposed copy Vt[b][d][n]
  k_prep<<<dim3(32, 8, 8), 256, 0, stream>>>(input, Abf, Vt);
  // 3) X = input @ W^T + b   (16384x512x512) -> bf16   [256 wg]
  k_gemm<true, true, 1, false><<<256, 512, 0, stream>>>(
      Abf, Wb, bias, nullptr, Xbf, 16384, 512, 512, 0, 0, 0);
  // 3b) D[row] = ||x_row||^2                            [4096 wg]
  k_rownorm<<<4096, 256, 0, stream>>>(Xbf, D);
  // 4) P = exp(X@X^T - d) (+ L32 partials when fused)   [512 wg, 1 batch/XCD]
  if (fused) {
    k_gemmS<true><<<512, 512, 0, stream>>>(Xbf, D, P, L32);
    // 4b) L[row] = sum of 32 partials (reads 2 MiB)     [64 wg]
    k_sumL<<<64, 256, 0, stream>>>(L32, L);
  } else {
    k_gemmS<false><<<512, 512, 0, stream>>>(Xbf, D, P, nullptr);
    // 4b) L[row] = sum of P row (re-reads P)            [4096 wg]
    k_sumP<<<4096, 256, 0, stream>>>(P, L);
  }
  // 5) out = (P @ Vt^T) / L per batch -> f32            [256 wg, 1 batch/XCD]
  k_gemm<false, false, 2, true><<<256, 512, 0, stream>>>(
      P, Vt, nullptr, L, out, 2048, 512, 2048,
      2048LL * 2048, 512LL * 2048, 2048LL * 512);
}

// Round 16
// 121.343 us; speedup vs baseline: 1.0175x; 1.0175x over previous
//
#include <hip/hip_runtime.h>
#include <hip/hip_bf16.h>
#include <stdint.h>

typedef short vbf16x8 __attribute__((ext_vector_type(8)));
typedef float vf32x4 __attribute__((ext_vector_type(4)));
typedef unsigned short u16;

__device__ __forceinline__ float bf2f(u16 u) {
  union { unsigned int i; float f; } v; v.i = ((unsigned int)u) << 16; return v.f;
}
__device__ __forceinline__ u16 f2bf(float f) {
  union { float f; unsigned int i; } v; v.f = f;
  return (u16)((v.i + 0x7fffu + ((v.i >> 16) & 1u)) >> 16);
}
__device__ __forceinline__ void gld16(const void* g, void* l) {
  __builtin_amdgcn_global_load_lds((const __attribute__((address_space(1))) void*)g,
                                   (__attribute__((address_space(3))) void*)l, 16, 0, 0);
}
template<int N> __device__ __forceinline__ void wait_vmcnt() {
  asm volatile("s_waitcnt vmcnt(%0)" :: "n"(N) : "memory");
}
__device__ __forceinline__ vbf16x8 ldsv(const u16* p) { return *(const vbf16x8*)p; }

// ---- W fp32 [512][512] -> bf16
__global__ __launch_bounds__(256) void k_convw(const float* __restrict__ W, u16* __restrict__ Wb) {
  int i = blockIdx.x * 256 + threadIdx.x;
  float4 x = ((const float4*)W)[i];
  ushort4 h;
  h.x = f2bf(x.x); h.y = f2bf(x.y); h.z = f2bf(x.z); h.w = f2bf(x.w);
  ((ushort4*)Wb)[i] = h;
}

// ---- input fp32 [8][2048][512] -> Abf bf16 (same layout) + Vt bf16 [8][512][2048]
__global__ __launch_bounds__(256) void k_prep(const float* __restrict__ in,
                                              u16* __restrict__ Abf, u16* __restrict__ Vt) {
  __shared__ u16 Ts[64][72];
  const int tid = threadIdx.x;
  const int n0 = blockIdx.x * 64, d0 = blockIdx.y * 64, b = blockIdx.z;
  const float* src = in + ((long long)b * 2048 + n0) * 512 + d0;
#pragma unroll
  for (int j = 0; j < 4; ++j) {
    int chunk = tid + 256 * j;
    int r = chunk >> 4, c = (chunk & 15) * 4;
    float4 x = *(const float4*)(src + (long long)r * 512 + c);
    ushort4 h;
    h.x = f2bf(x.x); h.y = f2bf(x.y); h.z = f2bf(x.z); h.w = f2bf(x.w);
    *(ushort4*)(Abf + ((long long)b * 2048 + n0 + r) * 512 + d0 + c) = h;
    Ts[c + 0][r] = h.x; Ts[c + 1][r] = h.y; Ts[c + 2][r] = h.z; Ts[c + 3][r] = h.w;
  }
  __syncthreads();
#pragma unroll
  for (int j = 0; j < 2; ++j) {
    int chunk = tid + 256 * j;
    int dr = chunk >> 3, c8 = (chunk & 7) * 8;
    vbf16x8 w = *(const vbf16x8*)&Ts[dr][c8];
    *(vbf16x8*)(Vt + ((long long)b * 512 + d0 + dr) * 2048 + n0 + c8) = w;
  }
}

// ---- row norms of X: D[row] = ||x_row||^2 ; one wave per row (16384 rows)
__global__ __launch_bounds__(256) void k_rownorm(const u16* __restrict__ X,
                                                 float* __restrict__ D) {
  const int row = blockIdx.x * 4 + (threadIdx.x >> 6);
  const int lane = threadIdx.x & 63;
  vbf16x8 v = *(const vbf16x8*)(X + (long long)row * 512 + lane * 8);
  float s = 0.0f;
#pragma unroll
  for (int j = 0; j < 8; ++j) { float x = bf2f((u16)v[j]); s = fmaf(x, x, s); }
  for (int o = 1; o < 64; o <<= 1) s += __shfl_xor(s, o);
  if (lane == 0) D[row] = s;
}

// ========== 256x128 GEMM (C = A @ Bt^T), BK=64, depth-2 tile prefetch ==========
// NORM=true (PV): accl = A @ ones, but REBALANCED — wave wc computes accl[m]
// only for m in {2wc, 2wc+1} (afr is identical across wc, so one wave per wr
// suffices per row-group). Per-wave MFMA/tile: 48 -> 36. Row sums shared via
// Lsh[256] + one barrier; values bitwise-identical to the all-wave version.
__device__ __forceinline__ void sround(const u16* g, int K, int k0, u16* ldsbuf,
                                       int r, int srow, int scol, int wv) {
  gld16(g + (long long)(r * 64 + srow) * K + k0 + scol, ldsbuf + r * 4096 + wv * 512);
}

template<bool OUTBF, bool BIAS, int MAP, bool NORM>
__global__ __launch_bounds__(512, 2) void k_gemm(const u16* __restrict__ A,
                                                 const u16* __restrict__ Bt,
                                                 const float* __restrict__ bias,
                                                 void* __restrict__ Cout,
                                                 int M, int N, int K,
                                                 long long sA, long long sB, long long sC) {
  __shared__ __align__(16) u16 As[3 * 16384];   // 3 x 256x64
  __shared__ __align__(16) u16 Bs[3 * 8192];    // 3 x 128x64
  __shared__ float Lsh[256];

  const int tid = threadIdx.x, lane = tid & 63, wv = tid >> 6;
  const int wr = wv >> 2, wc = wv & 3;

  const int lin = blockIdx.x;
  const int xcd = lin & 7, idx = lin >> 3;
  int zb, browi, bcoli;
  if constexpr (MAP == 1) { zb = 0; browi = xcd * 8 + (idx >> 2); bcoli = idx & 3; }  // GEMM1: 256 wg
  else { zb = xcd; browi = idx >> 2; bcoli = idx & 3; }                               // PV: 256 wg
  const int brow = browi * 256, bcol = bcoli * 128;
  const long long z = zb;

  const u16* gA = A + z * sA + (long long)brow * K;
  const u16* gB = Bt + z * sB + (long long)bcol * K;
  const int NT = K >> 6;

  const int srow = wv * 8 + (lane >> 3);
  const int scol = (((lane & 7) ^ ((lane >> 3) & 7)) << 3);
  const int rd0 = (lane & 15) * 64 + ((((lane >> 4)) ^ (lane & 7)) << 3);
  const int wrb = wr * 8192;
  const int wcb = wc * 2048;

  vf32x4 acc[8][2] = {};
  vf32x4 accl[8] = {};
  vbf16x8 afr[4], bfr[2];
  vbf16x8 ones;
  if constexpr (NORM) {
#pragma unroll
    for (int j = 0; j < 8; ++j) ones[j] = (short)0x3F80;   // bf16 1.0
  }

  u16 *A0 = As, *A1 = As + 16384, *A2 = As + 32768;
  u16 *B0 = Bs, *B1 = Bs + 8192, *B2 = Bs + 16384;

  sround(gA, K, 0, A0, 0, srow, scol, wv);
  sround(gA, K, 0, A0, 1, srow, scol, wv);
  sround(gA, K, 0, A0, 2, srow, scol, wv);
  sround(gA, K, 0, A0, 3, srow, scol, wv);
  sround(gB, K, 0, B0, 0, srow, scol, wv);
  sround(gB, K, 0, B0, 1, srow, scol, wv);
  sround(gA, K, 64, A1, 0, srow, scol, wv);
  sround(gA, K, 64, A1, 1, srow, scol, wv);
  sround(gA, K, 64, A1, 2, srow, scol, wv);
  sround(gA, K, 64, A1, 3, srow, scol, wv);
  sround(gB, K, 64, B1, 0, srow, scol, wv);
  sround(gB, K, 64, B1, 1, srow, scol, wv);

  for (int t = 0; t < NT; ++t) {
    const int k2 = (t + 2) * 64;
    const bool st = (t + 2 < NT);

    if (t < NT - 1) wait_vmcnt<6>(); else wait_vmcnt<0>();
    __builtin_amdgcn_sched_barrier(0);
    __builtin_amdgcn_s_barrier();
    __builtin_amdgcn_sched_barrier(0);

    // ---- phase 0: kh0, m0-3
#pragma unroll
    for (int n = 0; n < 2; ++n) bfr[n] = ldsv(B0 + wcb + n * 1024 + rd0);
#pragma unroll
    for (int i = 0; i < 4; ++i) afr[i] = ldsv(A0 + wrb + i * 1024 + rd0);
    if (st) { sround(gA, K, k2, A2, 0, srow, scol, wv); sround(gA, K, k2, A2, 1, srow, scol, wv); }
    __builtin_amdgcn_s_setprio(1);
#pragma unroll
    for (int i = 0; i < 4; ++i)
#pragma unroll
      for (int n = 0; n < 2; ++n)
        acc[i][n] = __builtin_amdgcn_mfma_f32_16x16x32_bf16(afr[i], bfr[n], acc[i][n], 0, 0, 0);
    if constexpr (NORM) {
#pragma unroll
      for (int i = 0; i < 4; ++i)
        if ((i >> 1) == wc)
          accl[i] = __builtin_amdgcn_mfma_f32_16x16x32_bf16(afr[i], ones, accl[i], 0, 0, 0);
    }
    __builtin_amdgcn_s_setprio(0);

    // ---- phase 1: kh0, m4-7
#pragma unroll
    for (int i = 0; i < 4; ++i) afr[i] = ldsv(A0 + wrb + (4 + i) * 1024 + rd0);
    if (st) sround(gA, K, k2, A2, 2, srow, scol, wv);
    __builtin_amdgcn_s_setprio(1);
#pragma unroll
    for (int i = 0; i < 4; ++i)
#pragma unroll
      for (int n = 0; n < 2; ++n)
        acc[4 + i][n] = __builtin_amdgcn_mfma_f32_16x16x32_bf16(afr[i], bfr[n], acc[4 + i][n], 0, 0, 0);
    if constexpr (NORM) {
#pragma unroll
      for (int i = 0; i < 4; ++i)
        if (2 + (i >> 1) == wc)
          accl[4 + i] = __builtin_amdgcn_mfma_f32_16x16x32_bf16(afr[i], ones, accl[4 + i], 0, 0, 0);
    }
    __builtin_amdgcn_s_setprio(0);

    // ---- phase 2: kh1, m0-3
#pragma unroll
    for (int n = 0; n < 2; ++n) bfr[n] = ldsv(B0 + wcb + n * 1024 + (rd0 ^ 32));
#pragma unroll
    for (int i = 0; i < 4; ++i) afr[i] = ldsv(A0 + wrb + i * 1024 + (rd0 ^ 32));
    if (st) { sround(gA, K, k2, A2, 3, srow, scol, wv); sround(gB, K, k2, B2, 0, srow, scol, wv); }
    __builtin_amdgcn_s_setprio(1);
#pragma unroll
    for (int i = 0; i < 4; ++i)
#pragma unroll
      for (int n = 0; n < 2; ++n)
        acc[i][n] = __builtin_amdgcn_mfma_f32_16x16x32_bf16(afr[i], bfr[n], acc[i][n], 0, 0, 0);
    if constexpr (NORM) {
#pragma unroll
      for (int i = 0; i < 4; ++i)
        if ((i >> 1) == wc)
          accl[i] = __builtin_amdgcn_mfma_f32_16x16x32_bf16(afr[i], ones, accl[i], 0, 0, 0);
    }
    __builtin_amdgcn_s_setprio(0);

    // ---- phase 3: kh1, m4-7
#pragma unroll
    for (int i = 0; i < 4; ++i) afr[i] = ldsv(A0 + wrb + (4 + i) * 1024 + (rd0 ^ 32));
    if (st) sround(gB, K, k2, B2, 1, srow, scol, wv);
    __builtin_amdgcn_s_setprio(1);
#pragma unroll
    for (int i = 0; i < 4; ++i)
#pragma unroll
      for (int n = 0; n < 2; ++n)
        acc[4 + i][n] = __builtin_amdgcn_mfma_f32_16x16x32_bf16(afr[i], bfr[n], acc[4 + i][n], 0, 0, 0);
    if constexpr (NORM) {
#pragma unroll
      for (int i = 0; i < 4; ++i)
        if (2 + (i >> 1) == wc)
          accl[4 + i] = __builtin_amdgcn_mfma_f32_16x16x32_bf16(afr[i], ones, accl[4 + i], 0, 0, 0);
    }
    __builtin_amdgcn_s_setprio(0);

    u16* ta = A0; A0 = A1; A1 = A2; A2 = ta;
    u16* tb = B0; B0 = B1; B1 = B2; B2 = tb;
  }

  // ---- share row sums (NORM): wave (wr,wc) owns rows of m in {2wc, 2wc+1}
  if constexpr (NORM) {
    if ((lane & 15) == 0) {
#pragma unroll
      for (int mm = 0; mm < 2; ++mm) {
        const int m = wc * 2 + mm;
#pragma unroll
        for (int r = 0; r < 4; ++r)
          Lsh[wr * 128 + m * 16 + (lane >> 4) * 4 + r] = accl[m][r];
      }
    }
    __builtin_amdgcn_s_barrier();
  }

  // ---- epilogue: C/D layout col=lane&15, row=(lane>>4)*4+r; NORM: /Lsh[row]
  const long long zc = z * sC;
#pragma unroll
  for (int m = 0; m < 8; ++m) {
    const int rloc = wr * 128 + m * 16 + (lane >> 4) * 4;
    const int row0 = brow + rloc;
#pragma unroll
    for (int n = 0; n < 2; ++n) {
      const int col = bcol + wc * 32 + n * 16 + (lane & 15);
      const float bv = BIAS ? bias[col] : 0.0f;
#pragma unroll
      for (int r = 0; r < 4; ++r) {
        float v = acc[m][n][r] + bv;
        if constexpr (NORM) v = v / Lsh[rloc + r];
        const long long off = zc + (long long)(row0 + r) * N + col;
        if (OUTBF) ((u16*)Cout)[off] = f2bf(v);
        else       ((float*)Cout)[off] = v;
      }
    }
  }
}

// ===== 256x256 S-GEMM -> P = exp(S - d), BK=32, depth-2, swizzled ============
// Main loop identical to R10/R13 (0 conflicts). Epilogue: exp (R13-proven) +
// LDS-transpose store: per m-pair, bounce the 64x256 bf16 sub-tile through the
// dead A-buffer (264-padded rows) and store coalesced dwordx4 (128 scalar u16
// stores/thread -> 16 vector stores/thread).
__device__ __forceinline__ void sr32(const u16* g, int K, int k0, u16* ldsbuf,
                                     int r, int srow, int scol, int wv) {
  gld16(g + (long long)(r * 128 + srow) * K + k0 + scol, ldsbuf + r * 4096 + wv * 512);
}

__global__ __launch_bounds__(512, 2) void k_gemmS(const u16* __restrict__ X,
                                                  const float* __restrict__ D,
                                                  u16* __restrict__ P) {
  constexpr int K = 512, N = 2048;
  __shared__ __align__(16) u16 As[3 * 8192];    // 3 x 256x32
  __shared__ __align__(16) u16 Bs[3 * 8192];    // 3 x 256x32

  const int tid = threadIdx.x, lane = tid & 63, wv = tid >> 6;
  const int wr = wv >> 2, wc = wv & 3;

  const int lin = blockIdx.x;
  const int xcd = lin & 7, idx = lin >> 3;
  const int brow = (idx >> 3) * 256, bcol = (idx & 7) * 256;
  const long long z = xcd;

  const u16* gA = X + z * (2048LL * 512) + (long long)brow * K;
  const u16* gB = X + z * (2048LL * 512) + (long long)bcol * K;
  const int NT = K >> 5;                // 16 tiles

  const int srow = wv * 16 + (lane >> 2);
  const int scol = (((lane & 3) ^ ((lane >> 3) & 3)) << 3);
  const int rd = (lane & 15) * 32 + ((((lane >> 4)) ^ (((lane & 15) >> 1) & 3)) << 3);
  const int wrb = wr * 4096;
  const int wcb = wc * 2048;

  vf32x4 acc[8][4] = {};
  vbf16x8 afr[4], bfr[4];

  u16 *A0 = As, *A1 = As + 8192, *A2 = As + 16384;
  u16 *B0 = Bs, *B1 = Bs + 8192, *B2 = Bs + 16384;

  sr32(gA, K, 0, A0, 0, srow, scol, wv);
  sr32(gA, K, 0, A0, 1, srow, scol, wv);
  sr32(gB, K, 0, B0, 0, srow, scol, wv);
  sr32(gB, K, 0, B0, 1, srow, scol, wv);
  sr32(gA, K, 32, A1, 0, srow, scol, wv);
  sr32(gA, K, 32, A1, 1, srow, scol, wv);
  sr32(gB, K, 32, B1, 0, srow, scol, wv);
  sr32(gB, K, 32, B1, 1, srow, scol, wv);

  for (int t = 0; t < NT; ++t) {
    const int k2 = (t + 2) * 32;
    const bool st = (t + 2 < NT);

    if (t < NT - 1) wait_vmcnt<4>(); else wait_vmcnt<0>();
    __builtin_amdgcn_sched_barrier(0);
    __builtin_amdgcn_s_barrier();
    __builtin_amdgcn_sched_barrier(0);

    // ---- phase 0: read B n0-3 + A m0-3; stage A(t+2); MFMA m0-3 x n0-3
#pragma unroll
    for (int n = 0; n < 4; ++n) bfr[n] = ldsv(B0 + wcb + n * 512 + rd);
#pragma unroll
    for (int i = 0; i < 4; ++i) afr[i] = ldsv(A0 + wrb + i * 512 + rd);
    if (st) { sr32(gA, K, k2, A2, 0, srow, scol, wv); sr32(gA, K, k2, A2, 1, srow, scol, wv); }
    __builtin_amdgcn_s_setprio(1);
#pragma unroll
    for (int i = 0; i < 4; ++i)
#pragma unroll
      for (int n = 0; n < 4; ++n)
        acc[i][n] = __builtin_amdgcn_mfma_f32_16x16x32_bf16(afr[i], bfr[n], acc[i][n], 0, 0, 0);
    __builtin_amdgcn_s_setprio(0);

    // ---- phase 1: read A m4-7; stage B(t+2); MFMA m4-7 x n0-3
#pragma unroll
    for (int i = 0; i < 4; ++i) afr[i] = ldsv(A0 + wrb + (4 + i) * 512 + rd);
    if (st) { sr32(gB, K, k2, B2, 0, srow, scol, wv); sr32(gB, K, k2, B2, 1, srow, scol, wv); }
    __builtin_amdgcn_s_setprio(1);
#pragma unroll
    for (int i = 0; i < 4; ++i)
#pragma unroll
      for (int n = 0; n < 4; ++n)
        acc[4 + i][n] = __builtin_amdgcn_mfma_f32_16x16x32_bf16(afr[i], bfr[n], acc[4 + i][n], 0, 0, 0);
    __builtin_amdgcn_s_setprio(0);

    u16* ta = A0; A0 = A1; A1 = A2; A2 = ta;
    u16* tb = B0; B0 = B1; B1 = B2; B2 = tb;
  }

  // ---- epilogue: P = exp(s - d), stored via LDS transpose (coalesced 16B)
  __builtin_amdgcn_s_barrier();                 // main-loop LDS reads complete
  u16* T = As;                                  // 64 x 264 u16 = 33 KB scratch
  const float* Dz = D + z * 2048;
  const long long zc = z * (2048LL * 2048);
#pragma unroll
  for (int m2 = 0; m2 < 4; ++m2) {
    if (m2) __builtin_amdgcn_s_barrier();       // previous m2's reads done
#pragma unroll
    for (int mm = 0; mm < 2; ++mm) {
      const int m = m2 * 2 + mm;
      const int trow0 = wr * 32 + mm * 16 + (lane >> 4) * 4;
#pragma unroll
      for (int r = 0; r < 4; ++r) {
        const float dv = Dz[brow + wr * 128 + m2 * 32 + mm * 16 + (lane >> 4) * 4 + r];
#pragma unroll
        for (int n = 0; n < 4; ++n) {
          const float p = __expf(acc[m][n][r] - dv);
          T[(trow0 + r) * 264 + wc * 64 + n * 16 + (lane & 15)] = f2bf(p);
        }
      }
    }
    __builtin_amdgcn_s_barrier();               // writes visible
#pragma unroll
    for (int j = 0; j < 4; ++j) {
      const int chunk = tid + 512 * j;          // 64 rows x 32 chunks
      const int trow = chunk >> 5, c8 = (chunk & 31) * 8;
      vbf16x8 w = *(const vbf16x8*)&T[trow * 264 + c8];
      const int grow = brow + (trow >> 5) * 128 + m2 * 32 + (trow & 31);
      *(vbf16x8*)&P[zc + (long long)grow * 2048 + bcol + c8] = w;
    }
  }
}

extern "C" void kernel_launch(void* const* d_in, const int* in_sizes, int n_in,
                              void* d_out, int out_size, void* d_ws, size_t ws_size,
                              hipStream_t stream) {
  const float* input = (const float*)d_in[0];   // [8][2048][512] f32
  const float* W     = (const float*)d_in[1];   // [512][512] f32
  const float* bias  = (const float*)d_in[2];   // [512] f32
  float* out = (float*)d_out;                   // [8][2048][512] f32

  char* ws = (char*)d_ws;
  u16* Xbf = (u16*)(ws);                        // 16 MiB
  u16* Vt  = (u16*)(ws + 16777216);             // 16 MiB
  u16* P   = (u16*)(ws + 2LL * 16777216);       // 64 MiB
  u16* Abf = (u16*)(ws + 2LL * 16777216);       // alias (first 16 MiB of P)
  u16* Wb  = (u16*)(ws + 3LL * 16777216);       // alias (0.5 MiB inside P)
  float* D = out;                               // 64 KB in out head (dead before PV)

  // 1) W -> bf16
  k_convw<<<256, 256, 0, stream>>>(W, Wb);
  // 2) input -> bf16 + transposed copy Vt[b][d][n]
  k_prep<<<dim3(32, 8, 8), 256, 0, stream>>>(input, Abf, Vt);
  // 3) X = input @ W^T + b   (16384x512x512) -> bf16   [256 wg]
  k_gemm<true, true, 1, false><<<256, 512, 0, stream>>>(
      Abf, Wb, bias, Xbf, 16384, 512, 512, 0, 0, 0);
  // 3b) D[row] = ||x_row||^2                            [4096 wg]
  k_rownorm<<<4096, 256, 0, stream>>>(Xbf, D);
  // 4) P = exp(X@X^T - d) per batch (2048x2048x512)     [512 wg, 1 batch/XCD]
  k_gemmS<<<512, 512, 0, stream>>>(Xbf, D, P);
  // 5) out = (P @ Vt^T) / (P @ ones) per batch -> f32   [256 wg, 1 batch/XCD]
  k_gemm<false, false, 2, true><<<256, 512, 0, stream>>>(
      P, Vt, nullptr, out, 2048, 512, 2048,
      2048LL * 2048, 512LL * 2048, 2048LL * 512);
}

// Round 17
// 108.973 us; speedup vs baseline: 1.1330x; 1.1135x over previous
//
#include <hip/hip_runtime.h>
#include <hip/hip_bf16.h>
#include <stdint.h>

typedef short vbf16x8 __attribute__((ext_vector_type(8)));
typedef float vf32x4 __attribute__((ext_vector_type(4)));
typedef unsigned short u16;

__device__ __forceinline__ float bf2f(u16 u) {
  union { unsigned int i; float f; } v; v.i = ((unsigned int)u) << 16; return v.f;
}
__device__ __forceinline__ u16 f2bf(float f) {
  union { float f; unsigned int i; } v; v.f = f;
  return (u16)((v.i + 0x7fffu + ((v.i >> 16) & 1u)) >> 16);
}
__device__ __forceinline__ void gld16(const void* g, void* l) {
  __builtin_amdgcn_global_load_lds((const __attribute__((address_space(1))) void*)g,
                                   (__attribute__((address_space(3))) void*)l, 16, 0, 0);
}
template<int N> __device__ __forceinline__ void wait_vmcnt() {
  asm volatile("s_waitcnt vmcnt(%0)" :: "n"(N) : "memory");
}
__device__ __forceinline__ vbf16x8 ldsv(const u16* p) { return *(const vbf16x8*)p; }

// ---- W fp32 [512][512] -> bf16
__global__ __launch_bounds__(256) void k_convw(const float* __restrict__ W, u16* __restrict__ Wb) {
  int i = blockIdx.x * 256 + threadIdx.x;
  float4 x = ((const float4*)W)[i];
  ushort4 h;
  h.x = f2bf(x.x); h.y = f2bf(x.y); h.z = f2bf(x.z); h.w = f2bf(x.w);
  ((ushort4*)Wb)[i] = h;
}

// ---- input fp32 [8][2048][512] -> Abf bf16 (same layout) + Vt bf16 [8][512][2048]
__global__ __launch_bounds__(256) void k_prep(const float* __restrict__ in,
                                              u16* __restrict__ Abf, u16* __restrict__ Vt) {
  __shared__ u16 Ts[64][72];
  const int tid = threadIdx.x;
  const int n0 = blockIdx.x * 64, d0 = blockIdx.y * 64, b = blockIdx.z;
  const float* src = in + ((long long)b * 2048 + n0) * 512 + d0;
#pragma unroll
  for (int j = 0; j < 4; ++j) {
    int chunk = tid + 256 * j;
    int r = chunk >> 4, c = (chunk & 15) * 4;
    float4 x = *(const float4*)(src + (long long)r * 512 + c);
    ushort4 h;
    h.x = f2bf(x.x); h.y = f2bf(x.y); h.z = f2bf(x.z); h.w = f2bf(x.w);
    *(ushort4*)(Abf + ((long long)b * 2048 + n0 + r) * 512 + d0 + c) = h;
    Ts[c + 0][r] = h.x; Ts[c + 1][r] = h.y; Ts[c + 2][r] = h.z; Ts[c + 3][r] = h.w;
  }
  __syncthreads();
#pragma unroll
  for (int j = 0; j < 2; ++j) {
    int chunk = tid + 256 * j;
    int dr = chunk >> 3, c8 = (chunk & 7) * 8;
    vbf16x8 w = *(const vbf16x8*)&Ts[dr][c8];
    *(vbf16x8*)(Vt + ((long long)b * 512 + d0 + dr) * 2048 + n0 + c8) = w;
  }
}

// ---- row norms of X: D[row] = ||x_row||^2 ; one wave per row (16384 rows)
__global__ __launch_bounds__(256) void k_rownorm(const u16* __restrict__ X,
                                                 float* __restrict__ D) {
  const int row = blockIdx.x * 4 + (threadIdx.x >> 6);
  const int lane = threadIdx.x & 63;
  vbf16x8 v = *(const vbf16x8*)(X + (long long)row * 512 + lane * 8);
  float s = 0.0f;
#pragma unroll
  for (int j = 0; j < 8; ++j) { float x = bf2f((u16)v[j]); s = fmaf(x, x, s); }
  for (int o = 1; o < 64; o <<= 1) s += __shfl_xor(s, o);
  if (lane == 0) D[row] = s;
}

// ========== 256x128 GEMM (C = A @ Bt^T), BK=64, depth-2 tile prefetch ==========
// (R7/R13-proven structure; used for GEMM1 only now)
__device__ __forceinline__ void sround(const u16* g, int K, int k0, u16* ldsbuf,
                                       int r, int srow, int scol, int wv) {
  gld16(g + (long long)(r * 64 + srow) * K + k0 + scol, ldsbuf + r * 4096 + wv * 512);
}

template<bool OUTBF, bool BIAS, int MAP>
__global__ __launch_bounds__(512, 2) void k_gemm(const u16* __restrict__ A,
                                                 const u16* __restrict__ Bt,
                                                 const float* __restrict__ bias,
                                                 void* __restrict__ Cout,
                                                 int M, int N, int K,
                                                 long long sA, long long sB, long long sC) {
  __shared__ __align__(16) u16 As[3 * 16384];   // 3 x 256x64
  __shared__ __align__(16) u16 Bs[3 * 8192];    // 3 x 128x64

  const int tid = threadIdx.x, lane = tid & 63, wv = tid >> 6;
  const int wr = wv >> 2, wc = wv & 3;

  const int lin = blockIdx.x;
  const int xcd = lin & 7, idx = lin >> 3;
  int zb, browi, bcoli;
  if constexpr (MAP == 1) { zb = 0; browi = xcd * 8 + (idx >> 2); bcoli = idx & 3; }  // GEMM1: 256 wg
  else { zb = xcd; browi = idx >> 2; bcoli = idx & 3; }
  const int brow = browi * 256, bcol = bcoli * 128;
  const long long z = zb;

  const u16* gA = A + z * sA + (long long)brow * K;
  const u16* gB = Bt + z * sB + (long long)bcol * K;
  const int NT = K >> 6;

  const int srow = wv * 8 + (lane >> 3);
  const int scol = (((lane & 7) ^ ((lane >> 3) & 7)) << 3);
  const int rd0 = (lane & 15) * 64 + ((((lane >> 4)) ^ (lane & 7)) << 3);
  const int wrb = wr * 8192;
  const int wcb = wc * 2048;

  vf32x4 acc[8][2] = {};
  vbf16x8 afr[4], bfr[2];

  u16 *A0 = As, *A1 = As + 16384, *A2 = As + 32768;
  u16 *B0 = Bs, *B1 = Bs + 8192, *B2 = Bs + 16384;

  sround(gA, K, 0, A0, 0, srow, scol, wv);
  sround(gA, K, 0, A0, 1, srow, scol, wv);
  sround(gA, K, 0, A0, 2, srow, scol, wv);
  sround(gA, K, 0, A0, 3, srow, scol, wv);
  sround(gB, K, 0, B0, 0, srow, scol, wv);
  sround(gB, K, 0, B0, 1, srow, scol, wv);
  sround(gA, K, 64, A1, 0, srow, scol, wv);
  sround(gA, K, 64, A1, 1, srow, scol, wv);
  sround(gA, K, 64, A1, 2, srow, scol, wv);
  sround(gA, K, 64, A1, 3, srow, scol, wv);
  sround(gB, K, 64, B1, 0, srow, scol, wv);
  sround(gB, K, 64, B1, 1, srow, scol, wv);

  for (int t = 0; t < NT; ++t) {
    const int k2 = (t + 2) * 64;
    const bool st = (t + 2 < NT);

    if (t < NT - 1) wait_vmcnt<6>(); else wait_vmcnt<0>();
    __builtin_amdgcn_sched_barrier(0);
    __builtin_amdgcn_s_barrier();
    __builtin_amdgcn_sched_barrier(0);

    // ---- phase 0: kh0, m0-3
#pragma unroll
    for (int n = 0; n < 2; ++n) bfr[n] = ldsv(B0 + wcb + n * 1024 + rd0);
#pragma unroll
    for (int i = 0; i < 4; ++i) afr[i] = ldsv(A0 + wrb + i * 1024 + rd0);
    if (st) { sround(gA, K, k2, A2, 0, srow, scol, wv); sround(gA, K, k2, A2, 1, srow, scol, wv); }
    __builtin_amdgcn_s_setprio(1);
#pragma unroll
    for (int i = 0; i < 4; ++i)
#pragma unroll
      for (int n = 0; n < 2; ++n)
        acc[i][n] = __builtin_amdgcn_mfma_f32_16x16x32_bf16(afr[i], bfr[n], acc[i][n], 0, 0, 0);
    __builtin_amdgcn_s_setprio(0);

    // ---- phase 1: kh0, m4-7
#pragma unroll
    for (int i = 0; i < 4; ++i) afr[i] = ldsv(A0 + wrb + (4 + i) * 1024 + rd0);
    if (st) sround(gA, K, k2, A2, 2, srow, scol, wv);
    __builtin_amdgcn_s_setprio(1);
#pragma unroll
    for (int i = 0; i < 4; ++i)
#pragma unroll
      for (int n = 0; n < 2; ++n)
        acc[4 + i][n] = __builtin_amdgcn_mfma_f32_16x16x32_bf16(afr[i], bfr[n], acc[4 + i][n], 0, 0, 0);
    __builtin_amdgcn_s_setprio(0);

    // ---- phase 2: kh1, m0-3
#pragma unroll
    for (int n = 0; n < 2; ++n) bfr[n] = ldsv(B0 + wcb + n * 1024 + (rd0 ^ 32));
#pragma unroll
    for (int i = 0; i < 4; ++i) afr[i] = ldsv(A0 + wrb + i * 1024 + (rd0 ^ 32));
    if (st) { sround(gA, K, k2, A2, 3, srow, scol, wv); sround(gB, K, k2, B2, 0, srow, scol, wv); }
    __builtin_amdgcn_s_setprio(1);
#pragma unroll
    for (int i = 0; i < 4; ++i)
#pragma unroll
      for (int n = 0; n < 2; ++n)
        acc[i][n] = __builtin_amdgcn_mfma_f32_16x16x32_bf16(afr[i], bfr[n], acc[i][n], 0, 0, 0);
    __builtin_amdgcn_s_setprio(0);

    // ---- phase 3: kh1, m4-7
#pragma unroll
    for (int i = 0; i < 4; ++i) afr[i] = ldsv(A0 + wrb + (4 + i) * 1024 + (rd0 ^ 32));
    if (st) sround(gB, K, k2, B2, 1, srow, scol, wv);
    __builtin_amdgcn_s_setprio(1);
#pragma unroll
    for (int i = 0; i < 4; ++i)
#pragma unroll
      for (int n = 0; n < 2; ++n)
        acc[4 + i][n] = __builtin_amdgcn_mfma_f32_16x16x32_bf16(afr[i], bfr[n], acc[4 + i][n], 0, 0, 0);
    __builtin_amdgcn_s_setprio(0);

    u16* ta = A0; A0 = A1; A1 = A2; A2 = ta;
    u16* tb = B0; B0 = B1; B1 = B2; B2 = tb;
  }

  // ---- epilogue: C/D layout col=lane&15, row=(lane>>4)*4+r
  const long long zc = z * sC;
#pragma unroll
  for (int m = 0; m < 8; ++m) {
    const int row0 = brow + wr * 128 + m * 16 + (lane >> 4) * 4;
#pragma unroll
    for (int n = 0; n < 2; ++n) {
      const int col = bcol + wc * 32 + n * 16 + (lane & 15);
      const float bv = BIAS ? bias[col] : 0.0f;
#pragma unroll
      for (int r = 0; r < 4; ++r) {
        const float v = acc[m][n][r] + bv;
        const long long off = zc + (long long)(row0 + r) * N + col;
        if (OUTBF) ((u16*)Cout)[off] = f2bf(v);
        else       ((float*)Cout)[off] = v;
      }
    }
  }
}

// ========== PV: out = (P @ Vt^T) / (P @ ones), 256x128 tile, BK=64 ===========
// Same proven skeleton, but 4x2 wave grid (wave tile 64x64, MF=4, NF=4): the
// ones-MFMA normalizer costs 1 per (m,kh) vs 4 main -> +25% (was +50% at the
// 2x4 grid). No conditionals, no sharing: each wave's accl rows == its acc rows.
__global__ __launch_bounds__(512, 2) void k_pv(const u16* __restrict__ P,
                                               const u16* __restrict__ Vt,
                                               float* __restrict__ out) {
  constexpr int K = 2048, N = 512;
  __shared__ __align__(16) u16 As[3 * 16384];   // 3 x 256x64 (P rows)
  __shared__ __align__(16) u16 Bs[3 * 8192];    // 3 x 128x64 (Vt rows)

  const int tid = threadIdx.x, lane = tid & 63, wv = tid >> 6;
  const int wr = wv >> 1, wc = wv & 1;          // 4x2 grid

  const int lin = blockIdx.x;
  const int xcd = lin & 7, idx = lin >> 3;      // 256 wg: 1 batch/XCD
  const int brow = (idx >> 2) * 256, bcol = (idx & 3) * 128;
  const long long z = xcd;

  const u16* gA = P + z * (2048LL * 2048) + (long long)brow * K;
  const u16* gB = Vt + z * (512LL * 2048) + (long long)bcol * K;
  const int NT = K >> 6;                        // 32 tiles

  const int srow = wv * 8 + (lane >> 3);
  const int scol = (((lane & 7) ^ ((lane >> 3) & 7)) << 3);
  const int rd0 = (lane & 15) * 64 + ((((lane >> 4)) ^ (lane & 7)) << 3);
  const int wrb = wr * 4096;                    // wr*64 rows * 64
  const int wcb = wc * 4096;                    // wc*64 rows * 64

  vf32x4 acc[4][4] = {};
  vf32x4 accl[4] = {};
  vbf16x8 afr[4], bfr[4];
  vbf16x8 ones;
#pragma unroll
  for (int j = 0; j < 8; ++j) ones[j] = (short)0x3F80;   // bf16 1.0

  u16 *A0 = As, *A1 = As + 16384, *A2 = As + 32768;
  u16 *B0 = Bs, *B1 = Bs + 8192, *B2 = Bs + 16384;

  sround(gA, K, 0, A0, 0, srow, scol, wv);
  sround(gA, K, 0, A0, 1, srow, scol, wv);
  sround(gA, K, 0, A0, 2, srow, scol, wv);
  sround(gA, K, 0, A0, 3, srow, scol, wv);
  sround(gB, K, 0, B0, 0, srow, scol, wv);
  sround(gB, K, 0, B0, 1, srow, scol, wv);
  sround(gA, K, 64, A1, 0, srow, scol, wv);
  sround(gA, K, 64, A1, 1, srow, scol, wv);
  sround(gA, K, 64, A1, 2, srow, scol, wv);
  sround(gA, K, 64, A1, 3, srow, scol, wv);
  sround(gB, K, 64, B1, 0, srow, scol, wv);
  sround(gB, K, 64, B1, 1, srow, scol, wv);

  for (int t = 0; t < NT; ++t) {
    const int k2 = (t + 2) * 64;
    const bool st = (t + 2 < NT);

    if (t < NT - 1) wait_vmcnt<6>(); else wait_vmcnt<0>();
    __builtin_amdgcn_sched_barrier(0);
    __builtin_amdgcn_s_barrier();
    __builtin_amdgcn_sched_barrier(0);

    // ---- phase 0: kh0, all m,n; stage A r0,r1,r2 (t+2)
#pragma unroll
    for (int n = 0; n < 4; ++n) bfr[n] = ldsv(B0 + wcb + n * 1024 + rd0);
#pragma unroll
    for (int i = 0; i < 4; ++i) afr[i] = ldsv(A0 + wrb + i * 1024 + rd0);
    if (st) {
      sround(gA, K, k2, A2, 0, srow, scol, wv);
      sround(gA, K, k2, A2, 1, srow, scol, wv);
      sround(gA, K, k2, A2, 2, srow, scol, wv);
    }
    __builtin_amdgcn_s_setprio(1);
#pragma unroll
    for (int i = 0; i < 4; ++i)
#pragma unroll
      for (int n = 0; n < 4; ++n)
        acc[i][n] = __builtin_amdgcn_mfma_f32_16x16x32_bf16(afr[i], bfr[n], acc[i][n], 0, 0, 0);
#pragma unroll
    for (int i = 0; i < 4; ++i)
      accl[i] = __builtin_amdgcn_mfma_f32_16x16x32_bf16(afr[i], ones, accl[i], 0, 0, 0);
    __builtin_amdgcn_s_setprio(0);

    // ---- phase 1: kh1, all m,n; stage A r3, B r0, B r1 (t+2)
#pragma unroll
    for (int n = 0; n < 4; ++n) bfr[n] = ldsv(B0 + wcb + n * 1024 + (rd0 ^ 32));
#pragma unroll
    for (int i = 0; i < 4; ++i) afr[i] = ldsv(A0 + wrb + i * 1024 + (rd0 ^ 32));
    if (st) {
      sround(gA, K, k2, A2, 3, srow, scol, wv);
      sround(gB, K, k2, B2, 0, srow, scol, wv);
      sround(gB, K, k2, B2, 1, srow, scol, wv);
    }
    __builtin_amdgcn_s_setprio(1);
#pragma unroll
    for (int i = 0; i < 4; ++i)
#pragma unroll
      for (int n = 0; n < 4; ++n)
        acc[i][n] = __builtin_amdgcn_mfma_f32_16x16x32_bf16(afr[i], bfr[n], acc[i][n], 0, 0, 0);
#pragma unroll
    for (int i = 0; i < 4; ++i)
      accl[i] = __builtin_amdgcn_mfma_f32_16x16x32_bf16(afr[i], ones, accl[i], 0, 0, 0);
    __builtin_amdgcn_s_setprio(0);

    u16* ta = A0; A0 = A1; A1 = A2; A2 = ta;
    u16* tb = B0; B0 = B1; B1 = B2; B2 = tb;
  }

  // ---- epilogue: divide by own-row L, write f32
  const long long zc = z * (2048LL * 512);
#pragma unroll
  for (int m = 0; m < 4; ++m) {
    const int row0 = brow + wr * 64 + m * 16 + (lane >> 4) * 4;
#pragma unroll
    for (int n = 0; n < 4; ++n) {
      const int col = bcol + wc * 64 + n * 16 + (lane & 15);
#pragma unroll
      for (int r = 0; r < 4; ++r) {
        out[zc + (long long)(row0 + r) * 512 + col] = acc[m][n][r] / accl[m][r];
      }
    }
  }
}

// ===== 256x256 S-GEMM -> P = exp(S - d), BK=32, depth-2, swizzled ============
// (exact R13 kernel: R10 main loop + exp epilogue with precomputed D)
__device__ __forceinline__ void sr32(const u16* g, int K, int k0, u16* ldsbuf,
                                     int r, int srow, int scol, int wv) {
  gld16(g + (long long)(r * 128 + srow) * K + k0 + scol, ldsbuf + r * 4096 + wv * 512);
}

__global__ __launch_bounds__(512, 2) void k_gemmS(const u16* __restrict__ X,
                                                  const float* __restrict__ D,
                                                  u16* __restrict__ P) {
  constexpr int K = 512, N = 2048;
  __shared__ __align__(16) u16 As[3 * 8192];    // 3 x 256x32
  __shared__ __align__(16) u16 Bs[3 * 8192];    // 3 x 256x32

  const int tid = threadIdx.x, lane = tid & 63, wv = tid >> 6;
  const int wr = wv >> 2, wc = wv & 3;

  const int lin = blockIdx.x;
  const int xcd = lin & 7, idx = lin >> 3;
  const int brow = (idx >> 3) * 256, bcol = (idx & 7) * 256;
  const long long z = xcd;

  const u16* gA = X + z * (2048LL * 512) + (long long)brow * K;
  const u16* gB = X + z * (2048LL * 512) + (long long)bcol * K;
  const int NT = K >> 5;                // 16 tiles

  const int srow = wv * 16 + (lane >> 2);
  const int scol = (((lane & 3) ^ ((lane >> 3) & 3)) << 3);
  const int rd = (lane & 15) * 32 + ((((lane >> 4)) ^ (((lane & 15) >> 1) & 3)) << 3);
  const int wrb = wr * 4096;
  const int wcb = wc * 2048;

  vf32x4 acc[8][4] = {};
  vbf16x8 afr[4], bfr[4];

  u16 *A0 = As, *A1 = As + 8192, *A2 = As + 16384;
  u16 *B0 = Bs, *B1 = Bs + 8192, *B2 = Bs + 16384;

  sr32(gA, K, 0, A0, 0, srow, scol, wv);
  sr32(gA, K, 0, A0, 1, srow, scol, wv);
  sr32(gB, K, 0, B0, 0, srow, scol, wv);
  sr32(gB, K, 0, B0, 1, srow, scol, wv);
  sr32(gA, K, 32, A1, 0, srow, scol, wv);
  sr32(gA, K, 32, A1, 1, srow, scol, wv);
  sr32(gB, K, 32, B1, 0, srow, scol, wv);
  sr32(gB, K, 32, B1, 1, srow, scol, wv);

  for (int t = 0; t < NT; ++t) {
    const int k2 = (t + 2) * 32;
    const bool st = (t + 2 < NT);

    if (t < NT - 1) wait_vmcnt<4>(); else wait_vmcnt<0>();
    __builtin_amdgcn_sched_barrier(0);
    __builtin_amdgcn_s_barrier();
    __builtin_amdgcn_sched_barrier(0);

    // ---- phase 0: read B n0-3 + A m0-3; stage A(t+2); MFMA m0-3 x n0-3
#pragma unroll
    for (int n = 0; n < 4; ++n) bfr[n] = ldsv(B0 + wcb + n * 512 + rd);
#pragma unroll
    for (int i = 0; i < 4; ++i) afr[i] = ldsv(A0 + wrb + i * 512 + rd);
    if (st) { sr32(gA, K, k2, A2, 0, srow, scol, wv); sr32(gA, K, k2, A2, 1, srow, scol, wv); }
    __builtin_amdgcn_s_setprio(1);
#pragma unroll
    for (int i = 0; i < 4; ++i)
#pragma unroll
      for (int n = 0; n < 4; ++n)
        acc[i][n] = __builtin_amdgcn_mfma_f32_16x16x32_bf16(afr[i], bfr[n], acc[i][n], 0, 0, 0);
    __builtin_amdgcn_s_setprio(0);

    // ---- phase 1: read A m4-7; stage B(t+2); MFMA m4-7 x n0-3
#pragma unroll
    for (int i = 0; i < 4; ++i) afr[i] = ldsv(A0 + wrb + (4 + i) * 512 + rd);
    if (st) { sr32(gB, K, k2, B2, 0, srow, scol, wv); sr32(gB, K, k2, B2, 1, srow, scol, wv); }
    __builtin_amdgcn_s_setprio(1);
#pragma unroll
    for (int i = 0; i < 4; ++i)
#pragma unroll
      for (int n = 0; n < 4; ++n)
        acc[4 + i][n] = __builtin_amdgcn_mfma_f32_16x16x32_bf16(afr[i], bfr[n], acc[4 + i][n], 0, 0, 0);
    __builtin_amdgcn_s_setprio(0);

    u16* ta = A0; A0 = A1; A1 = A2; A2 = ta;
    u16* tb = B0; B0 = B1; B1 = B2; B2 = tb;
  }

  // ---- epilogue: P = exp(s - d); C/D col=lane&15, row=(lane>>4)*4+r
  const float* Dz = D + z * 2048;
  const long long zc = z * (2048LL * 2048);
#pragma unroll
  for (int m = 0; m < 8; ++m) {
    const int row0 = brow + wr * 128 + m * 16 + (lane >> 4) * 4;
#pragma unroll
    for (int r = 0; r < 4; ++r) {
      const float dv = Dz[row0 + r];
#pragma unroll
      for (int n = 0; n < 4; ++n) {
        const int col = bcol + wc * 64 + n * 16 + (lane & 15);
        const float p = __expf(acc[m][n][r] - dv);
        P[zc + (long long)(row0 + r) * N + col] = f2bf(p);
      }
    }
  }
}

extern "C" void kernel_launch(void* const* d_in, const int* in_sizes, int n_in,
                              void* d_out, int out_size, void* d_ws, size_t ws_size,
                              hipStream_t stream) {
  const float* input = (const float*)d_in[0];   // [8][2048][512] f32
  const float* W     = (const float*)d_in[1];   // [512][512] f32
  const float* bias  = (const float*)d_in[2];   // [512] f32
  float* out = (float*)d_out;                   // [8][2048][512] f32

  char* ws = (char*)d_ws;
  u16* Xbf = (u16*)(ws);                        // 16 MiB
  u16* Vt  = (u16*)(ws + 16777216);             // 16 MiB
  u16* P   = (u16*)(ws + 2LL * 16777216);       // 64 MiB
  u16* Abf = (u16*)(ws + 2LL * 16777216);       // alias (first 16 MiB of P)
  u16* Wb  = (u16*)(ws + 3LL * 16777216);       // alias (0.5 MiB inside P)
  float* D = out;                               // 64 KB in out head (dead before PV)

  // 1) W -> bf16
  k_convw<<<256, 256, 0, stream>>>(W, Wb);
  // 2) input -> bf16 + transposed copy Vt[b][d][n]
  k_prep<<<dim3(32, 8, 8), 256, 0, stream>>>(input, Abf, Vt);
  // 3) X = input @ W^T + b   (16384x512x512) -> bf16   [256 wg]
  k_gemm<true, true, 1><<<256, 512, 0, stream>>>(
      Abf, Wb, bias, Xbf, 16384, 512, 512, 0, 0, 0);
  // 3b) D[row] = ||x_row||^2                            [4096 wg]
  k_rownorm<<<4096, 256, 0, stream>>>(Xbf, D);
  // 4) P = exp(X@X^T - d) per batch (2048x2048x512)     [512 wg, 1 batch/XCD]
  k_gemmS<<<512, 512, 0, stream>>>(Xbf, D, P);
  // 5) out = (P @ Vt^T) / (P @ ones) per batch -> f32   [256 wg, 1 batch/XCD]
  k_pv<<<256, 512, 0, stream>>>(P, Vt, out);
}